// Round 7
// baseline (149.886 us; speedup 1.0000x reference)
//
#include <hip/hip_runtime.h>

// DFMB PSROIAlign — separable (rank-1) weights, FLAT one-lane-per-(roi,bin).
//
// Per (roi,bin) the 16 subsamples live in a 3x3 pixel patch; per-pixel weight
// W[p][q] = AY[p]*AX[q] - BY[p]*BX[q], count = cntY*cntX (bilinear, keep-gate
// and bad11-gate all separable in ih/iw).
//
// R4-R6 lessons: block-structured version pinned at ~60us, VALUBusy 24%,
// occupancy 25% — latency-bound; compiler refuses to hold a 27-load batch in
// registers (VGPR stays 68, loads chunked ~2 pixels -> 4-9 L2 round-trips per
// bin, 4 bins serialized per thread). Source-level ILP forcing failed (R6) and
// smaller blocks regressed (R5). R7 flattens: one lane per (roi,bin), 1.47M
// lanes, no LDS, no barrier — one load batch per lane, latency hidden by TLP
// (4x the waves/CU). Side compute is 7x redundant but only ~5us chip-wide.
// Stores: out[n*490 + c*49 + bin]; adjacent lanes = adjacent bins -> dense
// lines, no write amplification (R1 lesson).

#define NC 10
#define NBIN 49
#define FH 34
#define FW 34
#define PLANE (FH * FW)
#define CSTRIDE 16   // floats per pixel in ftT (64B = one cache line)

__global__ __launch_bounds__(256) void prep_kernel(
    const float* __restrict__ ft, float* __restrict__ ftT)
{
    const int p = blockIdx.x * 256 + threadIdx.x;  // over 49*1156 pixels
    if (p >= NBIN * PLANE) return;
    float v[NC];
#pragma unroll
    for (int c = 0; c < NC; ++c) v[c] = ft[c * (NBIN * PLANE) + p];
    float4* d = reinterpret_cast<float4*>(ftT + (size_t)p * CSTRIDE);
    d[0] = make_float4(v[0], v[1], v[2], v[3]);
    d[1] = make_float4(v[4], v[5], v[6], v[7]);
    d[2] = make_float4(v[8], v[9], 0.f, 0.f);
}

// One axis side: A[3] bilinear weights, B[3] bad11-correction weights, count,
// patch origin P0. isY: B carries the (y1v||y2v) factor; !isY: (!x1v||!x2v).
__device__ __forceinline__ void side_compute(
    float st, float bs, float sb, int k, bool isY,
    float A[3], float B[3], float& cnt, int& P0)
{
    const float start = floorf(__fadd_rn(st, __fmul_rn((float)k, bs)));
#pragma unroll
    for (int i = 0; i < 4; ++i) {
        const float h = __fadd_rn(start, __fmul_rn((float)i + 0.5f, sb));
        const bool ok = (h > -1.0f) && (h < 34.0f);
        const int p1 = (int)floorf(h);
        const int p2 = (int)ceilf(h);
        const bool v1 = (p1 >= 0) && (p1 < 34);
        const bool v2 = (p2 >= 0) && (p2 < 34);
        const int p1c = min(max(p1, 0), 33);
        const int p2c = min(max(p2, 0), 33);
        const float d = __fsub_rn(h, (float)p1c);  // vs CLIPPED corner (ref)
        if (i == 0) P0 = p1c;                      // min (h increasing)
        const int i1 = p1c - P0, i2 = p2c - P0;    // in {0,1,2}
        const float t1 = ok ? (1.0f - d) : 0.0f;
        const float t2 = ok ? d : 0.0f;
        const bool bsel = isY ? (v1 || v2) : ((!v1) || (!v2));
        const float tb = (ok && bsel) ? (1.0f - d) : 0.0f;
        cnt += ok ? 1.0f : 0.0f;
#pragma unroll
        for (int p = 0; p < 3; ++p) {
            A[p] += (i1 == p) ? t1 : 0.0f;
            A[p] += (i2 == p) ? t2 : 0.0f;
            B[p] += (i1 == p) ? tb : 0.0f;
        }
    }
}

__global__ __launch_bounds__(256) void main_kernel(
    const float* __restrict__ rois, const float* __restrict__ ftT,
    const float* __restrict__ ft, float* __restrict__ out, int N, int use_t)
{
    const int i = blockIdx.x * 256 + threadIdx.x;
    if (i >= N * NBIN) return;
    const int n   = i / NBIN;          // magic-mul division
    const int bin = i - n * NBIN;
    const int ph  = bin / 7;
    const int pw  = bin - ph * 7;

    // roi coords / STRIDE(8) — *0.125f exact (pow2). 49 lanes/roi: broadcast.
    const float rsw = rois[n * 5 + 1] * 0.125f;
    const float rsh = rois[n * 5 + 2] * 0.125f;
    const float rew = rois[n * 5 + 3] * 0.125f;
    const float reh = rois[n * 5 + 4] * 0.125f;

    // Explicit _rn chain: floor/ceil/compare inputs must bit-match numpy fp32.
    float rheight = __fsub_rn(reh, rsh);
    if (!(rheight > 0.1f)) rheight = 0.1f;
    float rwidth = __fsub_rn(rew, rsw);
    if (!(rwidth > 0.1f)) rwidth = 0.1f;
    const float bsh   = __fdiv_rn(rheight, 7.0f);
    const float bsw   = __fdiv_rn(rwidth, 7.0f);
    const float sub_h = __fdiv_rn(bsh, 4.0f);
    const float sub_w = __fdiv_rn(bsw, 4.0f);

    float AY[3] = {0.f, 0.f, 0.f}, BY[3] = {0.f, 0.f, 0.f};
    float AX[3] = {0.f, 0.f, 0.f}, BX[3] = {0.f, 0.f, 0.f};
    float cntY = 0.f, cntX = 0.f;
    int Y0 = 0, X0 = 0;
    side_compute(rsh, bsh, sub_h, ph, true,  AY, BY, cntY, Y0);
    side_compute(rsw, bsw, sub_w, pw, false, AX, BX, cntX, X0);

    const int binbase = bin * PLANE;
    const int rowo[3] = {binbase + Y0 * FW,
                         binbase + min(Y0 + 1, FH - 1) * FW,
                         binbase + min(Y0 + 2, FH - 1) * FW};
    const int colo[3] = {X0, min(X0 + 1, FW - 1), min(X0 + 2, FW - 1)};

    float wgt[9];
    int   off[9];
#pragma unroll
    for (int p = 0; p < 3; ++p)
#pragma unroll
        for (int q = 0; q < 3; ++q) {
            const float w = AY[p] * AX[q] - BY[p] * BX[q];
            wgt[3 * p + q] = w;
            // zero-weight -> shared dummy pixel (plane origin): loads stay
            // batched/branch-free, masked lanes share one hot line.
            off[3 * p + q] = (w != 0.0f) ? (rowo[p] + colo[q]) : binbase;
        }

    float sum[NC];
#pragma unroll
    for (int c = 0; c < NC; ++c) sum[c] = 0.f;

    if (use_t) {
#pragma unroll
        for (int k = 0; k < 9; ++k) {
            const float* pix = ftT + (size_t)off[k] * CSTRIDE;
            const float4 a  = *(const float4*)pix;
            const float4 b  = *(const float4*)(pix + 4);
            const float2 c2 = *(const float2*)(pix + 8);
            const float w = wgt[k];
            sum[0] = fmaf(w, a.x, sum[0]);
            sum[1] = fmaf(w, a.y, sum[1]);
            sum[2] = fmaf(w, a.z, sum[2]);
            sum[3] = fmaf(w, a.w, sum[3]);
            sum[4] = fmaf(w, b.x, sum[4]);
            sum[5] = fmaf(w, b.y, sum[5]);
            sum[6] = fmaf(w, b.z, sum[6]);
            sum[7] = fmaf(w, b.w, sum[7]);
            sum[8] = fmaf(w, c2.x, sum[8]);
            sum[9] = fmaf(w, c2.y, sum[9]);
        }
    } else {
#pragma unroll
        for (int k = 0; k < 9; ++k) {
            const float w = wgt[k];
#pragma unroll
            for (int c = 0; c < NC; ++c)
                sum[c] = fmaf(w, ft[c * (NBIN * PLANE) + off[k]], sum[c]);
        }
    }

    const float cnt = cntY * cntX;
    const float inv = (cnt > 0.0f) ? __fdiv_rn(1.0f, cnt) : 1.0f;

    // out[n][c*49+bin]: adjacent lanes = adjacent bins -> dense lines.
    float* op = out + (size_t)n * (NC * NBIN) + bin;
#pragma unroll
    for (int c = 0; c < NC; ++c) op[c * NBIN] = sum[c] * inv;
}

extern "C" void kernel_launch(void* const* d_in, const int* in_sizes, int n_in,
                              void* d_out, int out_size, void* d_ws, size_t ws_size,
                              hipStream_t stream) {
    const float* ft   = (const float*)d_in[0];
    const float* rois = (const float*)d_in[1];
    float* out        = (float*)d_out;
    const int N = in_sizes[1] / 5;

    const size_t need = (size_t)NBIN * PLANE * CSTRIDE * sizeof(float);  // 3.63 MB
    const int use_t = (ws_size >= need) ? 1 : 0;
    float* ftT = (float*)d_ws;

    if (use_t) {
        const int npix = NBIN * PLANE;
        prep_kernel<<<(npix + 255) / 256, 256, 0, stream>>>(ft, ftT);
    }
    const long long total = (long long)N * NBIN;
    main_kernel<<<(int)((total + 255) / 256), 256, 0, stream>>>(rois, ftT, ft, out, N, use_t);
}

// Round 8
// 112.345 us; speedup vs baseline: 1.3342x; 1.3342x over previous
//
#include <hip/hip_runtime.h>
#include <hip/hip_fp16.h>

// DFMB PSROIAlign — separable (rank-1) weights + phase-split sides + fp16
// packed gather source.
//
// Per (roi,bin) the 16 subsamples live in a 3x3 pixel patch; per-pixel weight
// W[p][q] = AY[p]*AX[q] - BY[p]*BX[q], count = cntY*cntX.
//
// R7 lesson: perf is pinned by the vector-memory addresser/L1 line path —
// every gather's 64 lanes touch ~64 distinct 64B lines (pixel==line, no
// intra-wave sharing), so cost ~ #loads x lines, independent of occupancy
// (R5/R6/R7 all flat). R8 halves both: ftH packs 10 channels in 20B fp16
// (pixel stride 32B) -> 2 loads/pixel (b128+b32) = 18/bin instead of 27, and
// ~5 distinct lines per patch instead of 9. FMA uses float(half) operands ->
// v_fma_mix_f32 (no cvt cost). fp16 error ~0.003 << 0.086 threshold.

#define NC 10
#define NBIN 49
#define FH 34
#define FW 34
#define PLANE (FH * FW)
#define HSTRIDE 8    // dwords per pixel in ftH (32B: 5 used + 3 pad)
#define RPB 16       // rois per block
#define TSTRIDE 491  // out-tile row stride (odd -> conflict-free flush)
#define NSIDE 14

__global__ __launch_bounds__(256) void prep_kernel(
    const float* __restrict__ ft, unsigned int* __restrict__ ftH)
{
    const int p = blockIdx.x * 256 + threadIdx.x;  // over 49*1156 pixels
    if (p >= NBIN * PLANE) return;
    unsigned int h2[5];
#pragma unroll
    for (int c = 0; c < 5; ++c) {
        const __half lo = __float2half_rn(ft[(2 * c)     * (NBIN * PLANE) + p]);
        const __half hi = __float2half_rn(ft[(2 * c + 1) * (NBIN * PLANE) + p]);
        const __half2 hh = __halves2half2(lo, hi);
        h2[c] = *(const unsigned int*)&hh;
    }
    unsigned int* d = ftH + (size_t)p * HSTRIDE;
    *(uint4*)d = make_uint4(h2[0], h2[1], h2[2], h2[3]);
    d[4] = h2[4];
}

__device__ __forceinline__ void fma2(float w, unsigned int u, float& s0, float& s1)
{
    const __half2 h = *(const __half2*)&u;
    s0 = fmaf(w, __half2float(__low2half(h)),  s0);   // -> v_fma_mix_f32
    s1 = fmaf(w, __half2float(__high2half(h)), s1);
}

__global__ __launch_bounds__(256) void main_kernel(
    const float* __restrict__ rois, const unsigned int* __restrict__ ftH,
    const float* __restrict__ ft, float* __restrict__ out, int N, int use_t)
{
    __shared__ float sides[NSIDE][RPB][8];  // 7 KB
    __shared__ float tile[RPB][TSTRIDE];    // 31.4 KB

    const int r = threadIdx.x & (RPB - 1);  // roi within block
    const int s = threadIdx.x >> 4;         // slot 0..15
    const int n = blockIdx.x * RPB + r;
    const bool valid = (n < N);

    float rsw = 0.f, rsh = 0.f, rew = 0.f, reh = 0.f;
    if (valid) {
        rsw = rois[n * 5 + 1] * 0.125f;  // /STRIDE(8), exact pow2
        rsh = rois[n * 5 + 2] * 0.125f;
        rew = rois[n * 5 + 3] * 0.125f;
        reh = rois[n * 5 + 4] * 0.125f;
    }
    // Explicit _rn chain: floor/ceil/compare inputs must bit-match numpy fp32.
    float rheight = __fsub_rn(reh, rsh);
    if (!(rheight > 0.1f)) rheight = 0.1f;
    float rwidth = __fsub_rn(rew, rsw);
    if (!(rwidth > 0.1f)) rwidth = 0.1f;
    const float bsh   = __fdiv_rn(rheight, 7.0f);
    const float bsw   = __fdiv_rn(rwidth, 7.0f);
    const float sub_h = __fdiv_rn(bsh, 4.0f);
    const float sub_w = __fdiv_rn(bsw, 4.0f);

    // ---- phase 1: one axis-side per slot (slots 0..13 active) ----
    if (s < NSIDE) {
        const bool isY = (s < 7);
        const int  k   = isY ? s : s - 7;
        const float st = isY ? rsh : rsw;
        const float bs = isY ? bsh : bsw;
        const float sb = isY ? sub_h : sub_w;
        const float start = floorf(__fadd_rn(st, __fmul_rn((float)k, bs)));

        float A[3] = {0.f, 0.f, 0.f}, B[3] = {0.f, 0.f, 0.f};
        float cnt = 0.f;
        int P0 = 0;
#pragma unroll
        for (int i = 0; i < 4; ++i) {
            const float h = __fadd_rn(start, __fmul_rn((float)i + 0.5f, sb));
            const bool ok = (h > -1.0f) && (h < 34.0f);
            const int p1 = (int)floorf(h);
            const int p2 = (int)ceilf(h);
            const bool v1 = (p1 >= 0) && (p1 < 34);
            const bool v2 = (p2 >= 0) && (p2 < 34);
            const int p1c = min(max(p1, 0), 33);
            const int p2c = min(max(p2, 0), 33);
            const float d = __fsub_rn(h, (float)p1c);  // vs CLIPPED corner
            if (i == 0) P0 = p1c;                      // min (h increasing)
            const int i1 = p1c - P0, i2 = p2c - P0;    // in {0,1,2}
            const float t1 = ok ? (1.0f - d) : 0.0f;
            const float t2 = ok ? d : 0.0f;
            // bad11 = (!x1v || !x2v) && (y1v || y2v): X carries "invalid",
            // Y carries "valid".
            const bool bsel = isY ? (v1 || v2) : ((!v1) || (!v2));
            const float tb = (ok && bsel) ? (1.0f - d) : 0.0f;
            cnt += ok ? 1.0f : 0.0f;
#pragma unroll
            for (int p = 0; p < 3; ++p) {
                A[p] += (i1 == p) ? t1 : 0.0f;
                A[p] += (i2 == p) ? t2 : 0.0f;
                B[p] += (i1 == p) ? tb : 0.0f;
            }
        }
        float* sp = &sides[s][r][0];
        sp[0] = A[0]; sp[1] = A[1]; sp[2] = A[2];
        sp[3] = B[0]; sp[4] = B[1]; sp[5] = B[2];
        sp[6] = cnt;  sp[7] = (float)P0;
    }
    __syncthreads();

    // ---- phase 2: 4 bins/thread; fp16 packed gathers (18 loads/bin) ----
#pragma unroll
    for (int j = 0; j < 4; ++j) {
        const int bin = j * RPB + s;
        if (valid && bin < NBIN) {
            const int ph = bin / 7;
            const int pw = bin - ph * 7;

            const float4 ya = *(const float4*)&sides[ph][r][0];
            const float4 yb = *(const float4*)&sides[ph][r][4];
            const float4 xa = *(const float4*)&sides[7 + pw][r][0];
            const float4 xb = *(const float4*)&sides[7 + pw][r][4];
            const float AY[3] = {ya.x, ya.y, ya.z};
            const float BY[3] = {ya.w, yb.x, yb.y};
            const float cntY  = yb.z;
            const int   Y0    = (int)yb.w;
            const float AX[3] = {xa.x, xa.y, xa.z};
            const float BX[3] = {xa.w, xb.x, xb.y};
            const float cntX  = xb.z;
            const int   X0    = (int)xb.w;

            const int binbase = bin * PLANE;
            const int rowo[3] = {binbase + Y0 * FW,
                                 binbase + min(Y0 + 1, FH - 1) * FW,
                                 binbase + min(Y0 + 2, FH - 1) * FW};
            const int colo[3] = {X0, min(X0 + 1, FW - 1), min(X0 + 2, FW - 1)};

            float wgt[9];
            int   off[9];
#pragma unroll
            for (int p = 0; p < 3; ++p)
#pragma unroll
                for (int q = 0; q < 3; ++q) {
                    const float w = AY[p] * AX[q] - BY[p] * BX[q];
                    wgt[3 * p + q] = w;
                    // zero-weight -> shared dummy pixel (plane origin): loads
                    // stay batched, masked lanes share one hot line.
                    off[3 * p + q] = (w != 0.0f) ? (rowo[p] + colo[q]) : binbase;
                }

            float sum[NC];
#pragma unroll
            for (int c = 0; c < NC; ++c) sum[c] = 0.f;

            if (use_t) {
#pragma unroll
                for (int k = 0; k < 9; ++k) {
                    const unsigned int* pix = ftH + (size_t)off[k] * HSTRIDE;
                    const uint4 A = *(const uint4*)pix;   // ch0..7
                    const unsigned int B = pix[4];        // ch8,9
                    const float w = wgt[k];
                    fma2(w, A.x, sum[0], sum[1]);
                    fma2(w, A.y, sum[2], sum[3]);
                    fma2(w, A.z, sum[4], sum[5]);
                    fma2(w, A.w, sum[6], sum[7]);
                    fma2(w, B,   sum[8], sum[9]);
                }
            } else {
#pragma unroll
                for (int k = 0; k < 9; ++k) {
                    const float w = wgt[k];
#pragma unroll
                    for (int c = 0; c < NC; ++c)
                        sum[c] = fmaf(w, ft[c * (NBIN * PLANE) + off[k]], sum[c]);
                }
            }

            const float cnt = cntY * cntX;
            const float inv = (cnt > 0.0f) ? __fdiv_rn(1.0f, cnt) : 1.0f;
            float* tp = &tile[r][0];
#pragma unroll
            for (int c = 0; c < NC; ++c) tp[c * NBIN + bin] = sum[c] * inv;
        }
    }

    __syncthreads();

    // Coalesced flush: 16 rois x 490 contiguous floats each.
    const int n0 = blockIdx.x * RPB;
    for (int i = threadIdx.x; i < RPB * (NC * NBIN); i += 256) {
        const int row = i / (NC * NBIN);
        const int col = i - row * (NC * NBIN);
        const int n2 = n0 + row;
        if (n2 < N) out[(size_t)n2 * (NC * NBIN) + col] = tile[row][col];
    }
}

extern "C" void kernel_launch(void* const* d_in, const int* in_sizes, int n_in,
                              void* d_out, int out_size, void* d_ws, size_t ws_size,
                              hipStream_t stream) {
    const float* ft   = (const float*)d_in[0];
    const float* rois = (const float*)d_in[1];
    float* out        = (float*)d_out;
    const int N = in_sizes[1] / 5;

    const size_t need = (size_t)NBIN * PLANE * HSTRIDE * 4;  // 1.81 MB
    const int use_t = (ws_size >= need) ? 1 : 0;
    unsigned int* ftH = (unsigned int*)d_ws;

    if (use_t) {
        const int npix = NBIN * PLANE;
        prep_kernel<<<(npix + 255) / 256, 256, 0, stream>>>(ft, ftH);
    }
    main_kernel<<<(N + RPB - 1) / RPB, 256, 0, stream>>>(rois, ftH, ft, out, N, use_t);
}